// Round 7
// baseline (217.488 us; speedup 1.0000x reference)
//
#include <hip/hip_runtime.h>

// ---------------------------------------------------------------------------
// 12-qubit real statevector QNN — 2 waves per sample, 32 state floats/lane.
//
// Stored index y (12 bits): bit0 = WAVE bit p, bits1..6 = lane, bits7..11 = reg.
// stored(y) = psi(G^{-t} y) after t CNOT-ladders; G: y'_k = y_k ^ y_{k-1}.
// RY(w) layer t: pair mask m = G^t e_w = sum_{d subset t} e_{w+d}  -> bit0 set
// ONLY for w=0  => 44/48 gates wave-internal, 4 gates cross-wave (LDS).
// Side mask s = row_w(G^{16-t}); side parity = par(s&y); sign = side? +s : -s.
// <Z_w> mask z = {w, w-4, w-8}.
//
// R2-R5 lessons: 1-wave/sample (64 floats) cannot fit the allocator's
// 64-arch-VGPR budget; attributes (launch_bounds min, waves_per_eu(4,4),
// asm pins) never moved it — only AGPR copies or scratch spill (R5: 4MB
// writes). Fix: halve per-lane state so the default budget fits.
// ---------------------------------------------------------------------------

constexpr unsigned pair_mask(int t, int w) {
    unsigned m = 0;
    for (int d = 0; w + d < 12; ++d)
        if ((d & ~(unsigned)t) == 0) m |= 1u << (w + d);
    return m;
}
constexpr unsigned side_mask(int t, int w) {
    unsigned s = 16u - (unsigned)t;
    unsigned m = 0;
    for (int d = 0; d <= w; ++d)
        if (((unsigned)d & ~s) == 0) m |= 1u << (w - d);
    return m;
}
constexpr unsigned z_mask(int w) {
    unsigned m = 0;
    for (int u = w; u >= 0; u -= 4) m |= 1u << u;
    return m;
}

static_assert(pair_mask(1, 0) == 0b11u, "");
static_assert(pair_mask(2, 3) == ((1u << 3) | (1u << 5)), "");
static_assert(pair_mask(4, 7) == ((1u << 7) | (1u << 11)), "");
static_assert(side_mask(1, 2) == 0b111u, "");
static_assert(side_mask(4, 11) == ((1u << 11) | (1u << 7) | (1u << 3)), "");
static_assert(z_mask(9) == ((1u << 9) | (1u << 5) | (1u << 1)), "");
// cross-wave gates have only wave+lane mask bits (no reg bits)
static_assert((pair_mask(1, 0) >> 7) == 0u && (pair_mask(2, 0) >> 7) == 0u, "");
static_assert((pair_mask(3, 0) >> 7) == 0u && (pair_mask(4, 0) >> 7) == 0u, "");
// in-wave gates (w>=1) never touch the wave bit
static_assert((pair_mask(3, 1) & 1u) == 0u && (pair_mask(4, 5) & 1u) == 0u, "");

// In-wave RY butterfly over 32 regs.
// LM: lane-XOR mask; RM: reg-XOR mask; SW/SL/SR: side-parity masks (wave/lane/reg).
template <unsigned LM, unsigned RM, unsigned SW, unsigned SL, unsigned SR>
__device__ __forceinline__ void ry32(float (&v)[32], float c, float s,
                                     unsigned lane, unsigned p) {
    const float ss = (((unsigned)__popc(SL & lane) ^ (SW & p)) & 1u) ? s : -s;
    if constexpr (RM == 0u) {
#pragma unroll
        for (int r = 0; r < 32; ++r) {
            float pv = __shfl_xor(v[r], (int)LM, 64);
            float t = pv * ss;
            v[r] = (__builtin_popcount(SR & (unsigned)r) & 1) ? fmaf(c, v[r], -t)
                                                              : fmaf(c, v[r], t);
        }
    } else {
#pragma unroll
        for (int r = 0; r < 32; ++r) {
            const int r2 = r ^ (int)RM;
            if (r > r2) continue;  // each pair once
            float a = v[r], b = v[r2];
            float pa = (LM != 0u) ? __shfl_xor(b, (int)LM, 64) : b;
            float pb = (LM != 0u) ? __shfl_xor(a, (int)LM, 64) : a;
            float ta = pa * ss, tb = pb * ss;
            v[r]  = (__builtin_popcount(SR & (unsigned)r)  & 1) ? fmaf(c, a, -ta)
                                                                : fmaf(c, a, ta);
            v[r2] = (__builtin_popcount(SR & (unsigned)r2) & 1) ? fmaf(c, b, -tb)
                                                                : fmaf(c, b, tb);
        }
    }
}

#define RY_APPLY(T, W)                                                         \
    {                                                                          \
        const float c_ = __shfl(cv_, 16 + (W), 64);                            \
        const float s_ = __shfl(sv_, 16 + (W), 64);                            \
        ry32<((pair_mask(T, W) >> 1) & 63u), (pair_mask(T, W) >> 7),           \
             (side_mask(T, W) & 1u), ((side_mask(T, W) >> 1) & 63u),           \
             (side_mask(T, W) >> 7)>(v, c_, s_, lane, p);                      \
    }

// Cross-wave gate (wire 0, layer T): partner = other wave, lane^ML, same reg.
// side = wave bit p  =>  sign = p ? +s : -s.   2 chunks of 16 regs via LDS.
#define XGATE(T)                                                               \
    {                                                                          \
        const float c_ = __shfl(cv_, 16, 64);                                  \
        const float s_ = __shfl(sv_, 16, 64);                                  \
        const float ss = p ? s_ : -s_;                                         \
        constexpr unsigned ML = (pair_mask(T, 0) >> 1) & 63u;                  \
        _Pragma("unroll") for (int h = 0; h < 2; ++h) {                        \
            _Pragma("unroll") for (int cc = 0; cc < 16; ++cc)                  \
                xb[pr][p][cc][lane] = v[h * 16 + cc];                          \
            __syncthreads();                                                   \
            _Pragma("unroll") for (int cc = 0; cc < 16; ++cc) {                \
                float pv = xb[pr][p ^ 1u][cc][lane ^ ML];                      \
                v[h * 16 + cc] = fmaf(c_, v[h * 16 + cc], ss * pv);            \
            }                                                                  \
            __syncthreads();                                                   \
        }                                                                      \
    }

#define LAYER(T)                                                               \
    XGATE(T)                                                                   \
    RY_APPLY(T, 1) RY_APPLY(T, 2) RY_APPLY(T, 3) RY_APPLY(T, 4)                \
    RY_APPLY(T, 5) RY_APPLY(T, 6) RY_APPLY(T, 7) RY_APPLY(T, 8)                \
    RY_APPLY(T, 9) RY_APPLY(T, 10) RY_APPLY(T, 11)

__global__ void __launch_bounds__(256) qnn12_kernel(
    const float* __restrict__ state, const float* __restrict__ params,
    const float* __restrict__ head_w, const float* __restrict__ head_b,
    float* __restrict__ out, int B) {
    __shared__ float xb[2][2][16][64];  // [pair][wave][chunk-reg][lane], 16KB

    const int tid = threadIdx.x;
    const unsigned lane = (unsigned)(tid & 63);
    const int wid = tid >> 6;
    const int pr = wid >> 1;            // pair index within block (0..1)
    const unsigned p = (unsigned)(wid & 1);  // wave bit = stored-index bit 0
    const int sample = blockIdx.x * 2 + pr;
    const bool active = sample < B;

    // ---- angles: lanes 0..11 encoding angles, lanes 16..27 shared params
    float ang = 0.f;
    if (active && lane < 12u) ang = state[sample * 12 + (int)lane];
    else if (lane >= 16u && lane < 28u) ang = params[lane - 16u];
    float sv_, cv_;
    __sincosf(0.5f * ang, &sv_, &cv_);

    // ---- encoding product state: wire0 -> p, wires1..6 -> lane, 7..11 -> reg
    float pre;
    {
        float c0 = __shfl(cv_, 0, 64), s0 = __shfl(sv_, 0, 64);
        pre = p ? s0 : c0;
    }
#pragma unroll
    for (int j = 0; j < 6; ++j) {
        float cw = __shfl(cv_, 1 + j, 64), sw = __shfl(sv_, 1 + j, 64);
        pre *= ((lane >> j) & 1u) ? sw : cw;
    }
    float fc[5], fs[5];
#pragma unroll
    for (int k = 0; k < 5; ++k) {
        fc[k] = __shfl(cv_, 7 + k, 64);
        fs[k] = __shfl(sv_, 7 + k, 64);
    }

    float v[32];
    {
        float t4[16];
#pragma unroll
        for (int j = 0; j < 16; ++j) {
            float x = pre;
            x *= (j & 1) ? fs[0] : fc[0];
            x *= (j & 2) ? fs[1] : fc[1];
            x *= (j & 4) ? fs[2] : fc[2];
            x *= (j & 8) ? fs[3] : fc[3];
            t4[j] = x;
        }
#pragma unroll
        for (int r = 0; r < 32; ++r)
            v[r] = t4[r & 15] * ((r & 16) ? fs[4] : fc[4]);
    }

    // ---- 4 variational layers (CNOT ladders folded into masks)
    LAYER(1)
    LAYER(2)
    LAYER(3)
    LAYER(4)

    // ---- epilogue: per-lane a_w = +-hw[w] (lane/wave part of z-parity),
    //      W(r) = A0 + sum_{w=7..11} +-a_w with compile-time reg-parity signs.
    float a[12];
#pragma unroll
    for (int w = 0; w < 12; ++w) {
        const unsigned z = z_mask(w);
        const unsigned zl = (z >> 1) & 63u, zw = z & 1u;
        const int sgn = (int)(((unsigned)__popc(zl & lane) ^ (zw & p)) & 1u);
        const float h = head_w[w];
        a[w] = sgn ? -h : h;
    }
    const float A0 = ((a[0] + a[1]) + (a[2] + a[3])) + ((a[4] + a[5]) + a[6]);

    float acc = 0.f;
#pragma unroll
    for (int r = 0; r < 32; ++r) {
        float wr = A0;
        wr += (__builtin_popcount((z_mask(7) >> 7) & (unsigned)r) & 1) ? -a[7] : a[7];
        wr += (__builtin_popcount((z_mask(8) >> 7) & (unsigned)r) & 1) ? -a[8] : a[8];
        wr += (__builtin_popcount((z_mask(9) >> 7) & (unsigned)r) & 1) ? -a[9] : a[9];
        wr += (__builtin_popcount((z_mask(10) >> 7) & (unsigned)r) & 1) ? -a[10] : a[10];
        wr += (__builtin_popcount((z_mask(11) >> 7) & (unsigned)r) & 1) ? -a[11] : a[11];
        acc = fmaf(v[r] * wr, v[r], acc);
    }
#pragma unroll
    for (int off = 32; off > 0; off >>= 1) acc += __shfl_xor(acc, off, 64);

    // ---- combine the two waves of the pair via LDS
    float* red = &xb[0][0][0][0];
    if (lane == 0u) red[wid] = acc;
    __syncthreads();
    if (active && p == 0u && lane == 0u)
        out[sample] = red[wid] + red[wid | 1] + head_b[0];
}

extern "C" void kernel_launch(void* const* d_in, const int* in_sizes, int n_in,
                              void* d_out, int out_size, void* d_ws, size_t ws_size,
                              hipStream_t stream) {
    const float* state  = (const float*)d_in[0];
    const float* params = (const float*)d_in[1];
    const float* head_w = (const float*)d_in[2];
    const float* head_b = (const float*)d_in[3];
    float* out = (float*)d_out;

    const int B = in_sizes[0] / 12;      // 8192
    const int blocks = (B + 1) / 2;      // 2 samples/block, 2 waves/sample
    hipLaunchKernelGGL(qnn12_kernel, dim3(blocks), dim3(256), 0, stream,
                       state, params, head_w, head_b, out, B);
}

// Round 8
// 217.132 us; speedup vs baseline: 1.0016x; 1.0016x over previous
//
#include <hip/hip_runtime.h>

// ---------------------------------------------------------------------------
// 12-qubit real statevector QNN — 2 waves per sample, 32 state floats/lane.
//
// Stored index y (12 bits): bit0 = WAVE bit p, bits1..6 = lane, bits7..11 = reg.
// stored(y) = psi(G^{-t} y) after t CNOT-ladders; G: y'_k = y_k ^ y_{k-1}.
// RY(w) layer t: pair mask m = G^t e_w = sum_{d subset t} e_{w+d}  -> bit0 set
// ONLY for w=0  => 44/48 gates wave-internal, 4 gates cross-wave (LDS).
// Side mask s = row_w(G^{16-t}); side parity = par(s&y); sign = side? +s : -s.
// <Z_w> mask z = {w, w-4, w-8}.
//
// R2-R7 lessons: allocator persistently homes the state off the arch-VGPR
// file (R7: VGPR_Count=40, implied ~64 AGPRs/lane, VALU-busy 98us = 2.2x
// ideal from accvgpr round-trips around every DS op). Indirect knobs
// (launch_bounds min, waves_per_eu(4,4), asm pins) all failed. This round:
// the DIRECT knob — amdgpu_num_vgpr(96) requests 96 arch VGPRs outright.
// ---------------------------------------------------------------------------

constexpr unsigned pair_mask(int t, int w) {
    unsigned m = 0;
    for (int d = 0; w + d < 12; ++d)
        if ((d & ~(unsigned)t) == 0) m |= 1u << (w + d);
    return m;
}
constexpr unsigned side_mask(int t, int w) {
    unsigned s = 16u - (unsigned)t;
    unsigned m = 0;
    for (int d = 0; d <= w; ++d)
        if (((unsigned)d & ~s) == 0) m |= 1u << (w - d);
    return m;
}
constexpr unsigned z_mask(int w) {
    unsigned m = 0;
    for (int u = w; u >= 0; u -= 4) m |= 1u << u;
    return m;
}

static_assert(pair_mask(1, 0) == 0b11u, "");
static_assert(pair_mask(2, 3) == ((1u << 3) | (1u << 5)), "");
static_assert(pair_mask(4, 7) == ((1u << 7) | (1u << 11)), "");
static_assert(side_mask(1, 2) == 0b111u, "");
static_assert(side_mask(4, 11) == ((1u << 11) | (1u << 7) | (1u << 3)), "");
static_assert(z_mask(9) == ((1u << 9) | (1u << 5) | (1u << 1)), "");
// cross-wave gates have only wave+lane mask bits (no reg bits)
static_assert((pair_mask(1, 0) >> 7) == 0u && (pair_mask(2, 0) >> 7) == 0u, "");
static_assert((pair_mask(3, 0) >> 7) == 0u && (pair_mask(4, 0) >> 7) == 0u, "");
// in-wave gates (w>=1) never touch the wave bit
static_assert((pair_mask(3, 1) & 1u) == 0u && (pair_mask(4, 5) & 1u) == 0u, "");

// In-wave RY butterfly over 32 regs.
// LM: lane-XOR mask; RM: reg-XOR mask; SW/SL/SR: side-parity masks (wave/lane/reg).
template <unsigned LM, unsigned RM, unsigned SW, unsigned SL, unsigned SR>
__device__ __forceinline__ void ry32(float (&v)[32], float c, float s,
                                     unsigned lane, unsigned p) {
    const float ss = (((unsigned)__popc(SL & lane) ^ (SW & p)) & 1u) ? s : -s;
    if constexpr (RM == 0u) {
#pragma unroll
        for (int r = 0; r < 32; ++r) {
            float pv = __shfl_xor(v[r], (int)LM, 64);
            float t = pv * ss;
            v[r] = (__builtin_popcount(SR & (unsigned)r) & 1) ? fmaf(c, v[r], -t)
                                                              : fmaf(c, v[r], t);
        }
    } else {
#pragma unroll
        for (int r = 0; r < 32; ++r) {
            const int r2 = r ^ (int)RM;
            if (r > r2) continue;  // each pair once
            float a = v[r], b = v[r2];
            float pa = (LM != 0u) ? __shfl_xor(b, (int)LM, 64) : b;
            float pb = (LM != 0u) ? __shfl_xor(a, (int)LM, 64) : a;
            float ta = pa * ss, tb = pb * ss;
            v[r]  = (__builtin_popcount(SR & (unsigned)r)  & 1) ? fmaf(c, a, -ta)
                                                                : fmaf(c, a, ta);
            v[r2] = (__builtin_popcount(SR & (unsigned)r2) & 1) ? fmaf(c, b, -tb)
                                                                : fmaf(c, b, tb);
        }
    }
}

#define RY_APPLY(T, W)                                                         \
    {                                                                          \
        const float c_ = __shfl(cv_, 16 + (W), 64);                            \
        const float s_ = __shfl(sv_, 16 + (W), 64);                            \
        ry32<((pair_mask(T, W) >> 1) & 63u), (pair_mask(T, W) >> 7),           \
             (side_mask(T, W) & 1u), ((side_mask(T, W) >> 1) & 63u),           \
             (side_mask(T, W) >> 7)>(v, c_, s_, lane, p);                      \
    }

// Cross-wave gate (wire 0, layer T): partner = other wave, lane^ML, same reg.
// side = wave bit p  =>  sign = p ? +s : -s.   2 chunks of 16 regs via LDS.
#define XGATE(T)                                                               \
    {                                                                          \
        const float c_ = __shfl(cv_, 16, 64);                                  \
        const float s_ = __shfl(sv_, 16, 64);                                  \
        const float ss = p ? s_ : -s_;                                         \
        constexpr unsigned ML = (pair_mask(T, 0) >> 1) & 63u;                  \
        _Pragma("unroll") for (int h = 0; h < 2; ++h) {                        \
            _Pragma("unroll") for (int cc = 0; cc < 16; ++cc)                  \
                xb[pr][p][cc][lane] = v[h * 16 + cc];                          \
            __syncthreads();                                                   \
            _Pragma("unroll") for (int cc = 0; cc < 16; ++cc) {                \
                float pv = xb[pr][p ^ 1u][cc][lane ^ ML];                      \
                v[h * 16 + cc] = fmaf(c_, v[h * 16 + cc], ss * pv);            \
            }                                                                  \
            __syncthreads();                                                   \
        }                                                                      \
    }

#define LAYER(T)                                                               \
    XGATE(T)                                                                   \
    RY_APPLY(T, 1) RY_APPLY(T, 2) RY_APPLY(T, 3) RY_APPLY(T, 4)                \
    RY_APPLY(T, 5) RY_APPLY(T, 6) RY_APPLY(T, 7) RY_APPLY(T, 8)                \
    RY_APPLY(T, 9) RY_APPLY(T, 10) RY_APPLY(T, 11)

__global__ void __attribute__((amdgpu_flat_work_group_size(256, 256),
                               amdgpu_num_vgpr(96)))
qnn12_kernel(const float* __restrict__ state, const float* __restrict__ params,
             const float* __restrict__ head_w, const float* __restrict__ head_b,
             float* __restrict__ out, int B) {
    __shared__ float xb[2][2][16][64];  // [pair][wave][chunk-reg][lane], 16KB

    const int tid = threadIdx.x;
    const unsigned lane = (unsigned)(tid & 63);
    const int wid = tid >> 6;
    const int pr = wid >> 1;            // pair index within block (0..1)
    const unsigned p = (unsigned)(wid & 1);  // wave bit = stored-index bit 0
    const int sample = blockIdx.x * 2 + pr;
    const bool active = sample < B;

    // ---- angles: lanes 0..11 encoding angles, lanes 16..27 shared params
    float ang = 0.f;
    if (active && lane < 12u) ang = state[sample * 12 + (int)lane];
    else if (lane >= 16u && lane < 28u) ang = params[lane - 16u];
    float sv_, cv_;
    __sincosf(0.5f * ang, &sv_, &cv_);

    // ---- encoding product state: wire0 -> p, wires1..6 -> lane, 7..11 -> reg
    float pre;
    {
        float c0 = __shfl(cv_, 0, 64), s0 = __shfl(sv_, 0, 64);
        pre = p ? s0 : c0;
    }
#pragma unroll
    for (int j = 0; j < 6; ++j) {
        float cw = __shfl(cv_, 1 + j, 64), sw = __shfl(sv_, 1 + j, 64);
        pre *= ((lane >> j) & 1u) ? sw : cw;
    }
    float fc[5], fs[5];
#pragma unroll
    for (int k = 0; k < 5; ++k) {
        fc[k] = __shfl(cv_, 7 + k, 64);
        fs[k] = __shfl(sv_, 7 + k, 64);
    }

    float v[32];
    {
        float t4[16];
#pragma unroll
        for (int j = 0; j < 16; ++j) {
            float x = pre;
            x *= (j & 1) ? fs[0] : fc[0];
            x *= (j & 2) ? fs[1] : fc[1];
            x *= (j & 4) ? fs[2] : fc[2];
            x *= (j & 8) ? fs[3] : fc[3];
            t4[j] = x;
        }
#pragma unroll
        for (int r = 0; r < 32; ++r)
            v[r] = t4[r & 15] * ((r & 16) ? fs[4] : fc[4]);
    }

    // ---- 4 variational layers (CNOT ladders folded into masks)
    LAYER(1)
    LAYER(2)
    LAYER(3)
    LAYER(4)

    // ---- epilogue: per-lane a_w = +-hw[w] (lane/wave part of z-parity),
    //      W(r) = A0 + sum_{w=7..11} +-a_w with compile-time reg-parity signs.
    float a[12];
#pragma unroll
    for (int w = 0; w < 12; ++w) {
        const unsigned z = z_mask(w);
        const unsigned zl = (z >> 1) & 63u, zw = z & 1u;
        const int sgn = (int)(((unsigned)__popc(zl & lane) ^ (zw & p)) & 1u);
        const float h = head_w[w];
        a[w] = sgn ? -h : h;
    }
    const float A0 = ((a[0] + a[1]) + (a[2] + a[3])) + ((a[4] + a[5]) + a[6]);

    float acc = 0.f;
#pragma unroll
    for (int r = 0; r < 32; ++r) {
        float wr = A0;
        wr += (__builtin_popcount((z_mask(7) >> 7) & (unsigned)r) & 1) ? -a[7] : a[7];
        wr += (__builtin_popcount((z_mask(8) >> 7) & (unsigned)r) & 1) ? -a[8] : a[8];
        wr += (__builtin_popcount((z_mask(9) >> 7) & (unsigned)r) & 1) ? -a[9] : a[9];
        wr += (__builtin_popcount((z_mask(10) >> 7) & (unsigned)r) & 1) ? -a[10] : a[10];
        wr += (__builtin_popcount((z_mask(11) >> 7) & (unsigned)r) & 1) ? -a[11] : a[11];
        acc = fmaf(v[r] * wr, v[r], acc);
    }
#pragma unroll
    for (int off = 32; off > 0; off >>= 1) acc += __shfl_xor(acc, off, 64);

    // ---- combine the two waves of the pair via LDS
    float* red = &xb[0][0][0][0];
    if (lane == 0u) red[wid] = acc;
    __syncthreads();
    if (active && p == 0u && lane == 0u)
        out[sample] = red[wid] + red[wid | 1] + head_b[0];
}

extern "C" void kernel_launch(void* const* d_in, const int* in_sizes, int n_in,
                              void* d_out, int out_size, void* d_ws, size_t ws_size,
                              hipStream_t stream) {
    const float* state  = (const float*)d_in[0];
    const float* params = (const float*)d_in[1];
    const float* head_w = (const float*)d_in[2];
    const float* head_b = (const float*)d_in[3];
    float* out = (float*)d_out;

    const int B = in_sizes[0] / 12;      // 8192
    const int blocks = (B + 1) / 2;      // 2 samples/block, 2 waves/sample
    hipLaunchKernelGGL(qnn12_kernel, dim3(blocks), dim3(256), 0, stream,
                       state, params, head_w, head_b, out, B);
}